// Round 1
// baseline (47.869 us; speedup 1.0000x reference)
//
#include <hip/hip_runtime.h>
#include <cmath>

// out[b,o] = bias[o] + sum_i x[b,i] * (w[i,o] + (|w[i,o]|+1e-15)*noise[b,i,o])
// BS=64, IN_F=1024, OUT_F=1024. Memory-bound on the 256 MiB noise stream.

constexpr int BS    = 64;
constexpr int IN_F  = 1024;
constexpr int OUT_F = 1024;
constexpr int ICH   = 8;             // i-chunks for extra parallelism
constexpr int CHUNK = IN_F / ICH;    // 128

// ---- Kernel 1: per-(i-chunk, b) partial sums over 256 threads x 4 o's ----
__global__ __launch_bounds__(256) void bridgeout_partial(
    const float* __restrict__ x, const float* __restrict__ w,
    const float* __restrict__ noise, float* __restrict__ partials) {
  const int ic = blockIdx.x;   // i-chunk
  const int b  = blockIdx.y;   // batch sample
  const int t  = threadIdx.x;
  const int o  = t << 2;       // 4 consecutive outputs per thread

  __shared__ float xs[CHUNK];
  if (t < CHUNK) xs[t] = x[b * IN_F + ic * CHUNK + t];
  __syncthreads();

  const float* wp = w + (size_t)(ic * CHUNK) * OUT_F + o;
  const float* np = noise + ((size_t)b * IN_F + (size_t)(ic * CHUNK)) * OUT_F + o;

  float ax = 0.f, ay = 0.f, az = 0.f, aw = 0.f;
#pragma unroll 4
  for (int i = 0; i < CHUNK; ++i) {
    const float xv = xs[i];
    const float4 w4 = *reinterpret_cast<const float4*>(wp);
    const float4 n4 = *reinterpret_cast<const float4*>(np);
    // w_noisy = w + (|w|+1e-15)*noise ; acc += x * w_noisy
    ax = fmaf(xv, fmaf(fabsf(w4.x) + 1e-15f, n4.x, w4.x), ax);
    ay = fmaf(xv, fmaf(fabsf(w4.y) + 1e-15f, n4.y, w4.y), ay);
    az = fmaf(xv, fmaf(fabsf(w4.z) + 1e-15f, n4.z, w4.z), az);
    aw = fmaf(xv, fmaf(fabsf(w4.w) + 1e-15f, n4.w, w4.w), aw);
    wp += OUT_F;
    np += OUT_F;
  }
  float4 acc = make_float4(ax, ay, az, aw);
  *reinterpret_cast<float4*>(partials + (size_t)(ic * BS + b) * OUT_F + o) = acc;
}

// ---- Kernel 2: reduce ICH partials + bias -> out (fully overwrites out) ----
__global__ __launch_bounds__(256) void bridgeout_reduce(
    const float* __restrict__ partials, const float* __restrict__ bias,
    float* __restrict__ out) {
  const int idx = blockIdx.x * 256 + threadIdx.x;
  const int e = idx << 2;                 // element index in [0, BS*OUT_F)
  if (e >= BS * OUT_F) return;
  const int b = e >> 10;                  // / OUT_F
  const int o = e & (OUT_F - 1);
  float4 a = *reinterpret_cast<const float4*>(bias + o);
#pragma unroll
  for (int c = 0; c < ICH; ++c) {
    const float4 p = *reinterpret_cast<const float4*>(
        partials + (size_t)(c * BS + b) * OUT_F + o);
    a.x += p.x; a.y += p.y; a.z += p.z; a.w += p.w;
  }
  *reinterpret_cast<float4*>(out + e) = a;
}

// ---- Fallback: fused single-pass (grid = BS), used only if ws too small ----
__global__ __launch_bounds__(256) void bridgeout_fused(
    const float* __restrict__ x, const float* __restrict__ w,
    const float* __restrict__ bias, const float* __restrict__ noise,
    float* __restrict__ out) {
  const int b = blockIdx.x;
  const int t = threadIdx.x;
  const int o = t << 2;

  __shared__ float xs[IN_F];
  for (int i = t; i < IN_F; i += 256) xs[i] = x[b * IN_F + i];
  __syncthreads();

  const float* wp = w + o;
  const float* np = noise + (size_t)b * IN_F * OUT_F + o;
  float ax = 0.f, ay = 0.f, az = 0.f, aw = 0.f;
#pragma unroll 4
  for (int i = 0; i < IN_F; ++i) {
    const float xv = xs[i];
    const float4 w4 = *reinterpret_cast<const float4*>(wp);
    const float4 n4 = *reinterpret_cast<const float4*>(np);
    ax = fmaf(xv, fmaf(fabsf(w4.x) + 1e-15f, n4.x, w4.x), ax);
    ay = fmaf(xv, fmaf(fabsf(w4.y) + 1e-15f, n4.y, w4.y), ay);
    az = fmaf(xv, fmaf(fabsf(w4.z) + 1e-15f, n4.z, w4.z), az);
    aw = fmaf(xv, fmaf(fabsf(w4.w) + 1e-15f, n4.w, w4.w), aw);
    wp += OUT_F;
    np += OUT_F;
  }
  const float4 bi = *reinterpret_cast<const float4*>(bias + o);
  float4 acc = make_float4(ax + bi.x, ay + bi.y, az + bi.z, aw + bi.w);
  *reinterpret_cast<float4*>(out + (size_t)b * OUT_F + o) = acc;
}

extern "C" void kernel_launch(void* const* d_in, const int* in_sizes, int n_in,
                              void* d_out, int out_size, void* d_ws, size_t ws_size,
                              hipStream_t stream) {
  const float* x     = (const float*)d_in[0];
  const float* w     = (const float*)d_in[1];
  const float* bias  = (const float*)d_in[2];
  const float* noise = (const float*)d_in[3];
  float* out = (float*)d_out;

  const size_t need = (size_t)ICH * BS * OUT_F * sizeof(float);  // 2 MiB
  if (ws_size >= need) {
    float* partials = (float*)d_ws;
    dim3 g1(ICH, BS);
    bridgeout_partial<<<g1, 256, 0, stream>>>(x, w, noise, partials);
    const int nthr = BS * OUT_F / 4;                  // 16384 threads
    bridgeout_reduce<<<(nthr + 255) / 256, 256, 0, stream>>>(partials, bias, out);
  } else {
    bridgeout_fused<<<BS, 256, 0, stream>>>(x, w, bias, noise, out);
  }
}